// Round 1
// baseline (1227.367 us; speedup 1.0000x reference)
//
#include <hip/hip_runtime.h>
#include <math.h>

#define TT 3
#define LL 3
#define EE 50000
#define NN 1000000
#define RR 200
#define NRELC 401
#define HH 256
#define BB 8
#define KTOP 1000

__device__ __forceinline__ float sigmoidf_(float x) {
    if (x >= 0.f) { return 1.f / (1.f + expf(-x)); }
    float z = expf(x); return z / (1.f + z);
}

// ---------------- Phase A: LSTMs ----------------
// One block per (l, dir, b): 48 blocks x 256 threads. Thread t owns hidden idx t
// (gate rows t, 256+t, 512+t, 768+t). Sequence inputs take only two distinct
// values per batch: q = emb[input_r[b]] and e = emb[400]; precompute both pre's.
__global__ __launch_bounds__(256) void lstm_kernel(
    const int* __restrict__ input_r, const float* __restrict__ emb,
    const float* __restrict__ Wih_f, const float* __restrict__ Whh_f,
    const float* __restrict__ bih_f, const float* __restrict__ bhh_f,
    const float* __restrict__ Wih_b, const float* __restrict__ Whh_b,
    const float* __restrict__ bih_b, const float* __restrict__ bhh_b,
    float* __restrict__ hbuf)
{
    int blk = blockIdx.x;          // l*16 + dir*8 + b
    int l   = blk >> 4;
    int dir = (blk >> 3) & 1;
    int b   = blk & 7;
    int tid = threadIdx.x;

    const float* Wih = (dir ? Wih_b : Wih_f) + (size_t)l * 4 * HH * HH;
    const float* Whh = (dir ? Whh_b : Whh_f) + (size_t)l * 4 * HH * HH;
    const float* bih = (dir ? bih_b : bih_f) + l * 4 * HH;
    const float* bhh = (dir ? bhh_b : bhh_f) + l * 4 * HH;

    __shared__ float xq[HH], xe[HH], h[HH];
    int r = input_r[b];
    xq[tid] = emb[(size_t)r * HH + tid];
    xe[tid] = emb[(size_t)(NRELC - 1) * HH + tid];
    h[tid] = 0.f;
    __syncthreads();

    float preq[4], pree[4];
    for (int g = 0; g < 4; ++g) {
        const float4* wr  = (const float4*)(Wih + (size_t)(g * HH + tid) * HH);
        const float4* x4q = (const float4*)xq;
        const float4* x4e = (const float4*)xe;
        float aq = 0.f, ae = 0.f;
        for (int k = 0; k < HH / 4; ++k) {
            float4 w4 = wr[k];
            float4 q4 = x4q[k]; float4 e4 = x4e[k];
            aq += w4.x * q4.x + w4.y * q4.y + w4.z * q4.z + w4.w * q4.w;
            ae += w4.x * e4.x + w4.y * e4.y + w4.z * e4.z + w4.w * e4.w;
        }
        float bsum = bih[g * HH + tid] + bhh[g * HH + tid];
        preq[g] = aq + bsum;
        pree[g] = ae + bsum;
    }

    float c = 0.f;
    for (int step = 0; step < 4; ++step) {
        bool use_e = dir ? (step == 0) : (step == 3);
        float gate[4];
        for (int g = 0; g < 4; ++g) {
            const float4* wr = (const float4*)(Whh + (size_t)(g * HH + tid) * HH);
            const float4* h4 = (const float4*)h;
            float a = 0.f;
            for (int k = 0; k < HH / 4; ++k) {
                float4 w4 = wr[k]; float4 hv = h4[k];
                a += w4.x * hv.x + w4.y * hv.y + w4.z * hv.z + w4.w * hv.w;
            }
            gate[g] = a + (use_e ? pree[g] : preq[g]);
        }
        float iv = sigmoidf_(gate[0]);
        float fv = sigmoidf_(gate[1]);
        float gv = tanhf(gate[2]);
        float ov = sigmoidf_(gate[3]);
        c = fv * c + iv * gv;
        float hn = ov * tanhf(c);
        __syncthreads();          // all gate reads of h done
        h[tid] = hn;
        __syncthreads();
        // fwd stores scan steps 0..2 at t=step; bwd (scan over reversed seq)
        // stores steps 1..3 at t=3-step (hb[t] = hs_rev[3-t]).
        int t_out = dir ? (3 - step) : step;
        if (t_out <= 2)
            hbuf[(((size_t)(l * 2 + dir) * BB + b) * 3 + t_out) * HH + tid] = hn;
    }
}

// ---------------- Phase A: logits + softmax ----------------
// One block per (t, b, l): 72 blocks. logits[n] = linW[n,:256].hf + linW[n,256:].hb + linb[n]
// then w = softmax(logits / 10).
__global__ __launch_bounds__(256) void logits_kernel(
    const float* __restrict__ hbuf, const float* __restrict__ linW,
    const float* __restrict__ linb, float* __restrict__ wbuf)
{
    int blk = blockIdx.x;          // t*24 + b*3 + l
    int l = blk % 3; int b = (blk / 3) & 7; int t = blk / 24;
    int tid = threadIdx.x;

    __shared__ float hf[HH], hb[HH];
    __shared__ float logits[NRELC];
    __shared__ float red[256];
    hf[tid] = hbuf[(((size_t)(l * 2 + 0) * BB + b) * 3 + t) * HH + tid];
    hb[tid] = hbuf[(((size_t)(l * 2 + 1) * BB + b) * 3 + t) * HH + tid];
    __syncthreads();

    for (int n = tid; n < NRELC; n += 256) {
        const float4* wr  = (const float4*)(linW + (size_t)n * 2 * HH);
        const float4* hf4 = (const float4*)hf;
        const float4* hb4 = (const float4*)hb;
        float a = 0.f;
        for (int k = 0; k < HH / 4; ++k) {
            float4 w4 = wr[k]; float4 hv = hf4[k];
            a += w4.x * hv.x + w4.y * hv.y + w4.z * hv.z + w4.w * hv.w;
        }
        for (int k = 0; k < HH / 4; ++k) {
            float4 w4 = wr[HH / 4 + k]; float4 hv = hb4[k];
            a += w4.x * hv.x + w4.y * hv.y + w4.z * hv.z + w4.w * hv.w;
        }
        logits[n] = a + linb[n];
    }
    __syncthreads();

    float m = -1e30f;
    for (int n = tid; n < NRELC; n += 256) m = fmaxf(m, logits[n]);
    red[tid] = m; __syncthreads();
    for (int s2 = 128; s2 > 0; s2 >>= 1) {
        if (tid < s2) red[tid] = fmaxf(red[tid], red[tid + s2]);
        __syncthreads();
    }
    m = red[0];
    __syncthreads();

    float ssum = 0.f;
    float ev[2] = {0.f, 0.f};
    int cnt = 0;
    for (int n = tid; n < NRELC; n += 256) {
        float e = expf((logits[n] - m) * 0.1f);
        ev[cnt++] = e;
        ssum += e;
    }
    red[tid] = ssum; __syncthreads();
    for (int s2 = 128; s2 > 0; s2 >>= 1) {
        if (tid < s2) red[tid] += red[tid + s2];
        __syncthreads();
    }
    float denom = red[0];

    cnt = 0;
    for (int n = tid; n < NRELC; n += 256)
        wbuf[((size_t)t * 24 + b * 3 + l) * NRELC + n] = ev[cnt++] / denom;
}

// ---------------- utility fills ----------------
__global__ void fill_zero_f(float* __restrict__ p, int n) {
    int i = blockIdx.x * 256 + threadIdx.x;
    if (i < n) p[i] = 0.f;
}
__global__ void fill_zero_i(int* __restrict__ p, int n) {
    int i = blockIdx.x * 256 + threadIdx.x;
    if (i < n) p[i] = 0;
}

// ---------------- hop 0: one-hot input ----------------
__global__ void seed0_kernel(const int* __restrict__ input_x,
                             const float* __restrict__ w0, float* __restrict__ s) {
    int i = threadIdx.x;
    if (i < 24) {
        int b = i / 3;
        s[(size_t)i * EE + input_x[b]] = w0[(size_t)i * NRELC + (NRELC - 1)];
    }
}

__global__ __launch_bounds__(256) void hop0_scan(
    const int* __restrict__ heads, const int* __restrict__ tails,
    const int* __restrict__ tails2, const int* __restrict__ rels,
    const int* __restrict__ input_x, const float* __restrict__ w0,
    float* __restrict__ s)
{
    __shared__ int xs[BB];
    if (threadIdx.x < BB) xs[threadIdx.x] = input_x[threadIdx.x];
    __syncthreads();
    int i = blockIdx.x * 256 + threadIdx.x;
    if (i >= NN) return;
    int h = heads[i], t2 = tails2[i];
    bool any = false;
    #pragma unroll
    for (int b = 0; b < BB; ++b) any = any || (h == xs[b]) || (t2 == xs[b]);
    if (!any) return;
    int tl = tails[i], rr = rels[i];
    for (int b = 0; b < BB; ++b) {
        if (h == xs[b])
            for (int l = 0; l < LL; ++l)
                atomicAdd(&s[(size_t)(b * 3 + l) * EE + tl], w0[(b * 3 + l) * NRELC + rr]);
        if (t2 == xs[b])
            for (int l = 0; l < LL; ++l)
                atomicAdd(&s[(size_t)(b * 3 + l) * EE + h], w0[(b * 3 + l) * NRELC + rr + RR]);
    }
}

// ---------------- normalization ----------------
__global__ __launch_bounds__(256) void row_sums_kernel(const float* __restrict__ s,
                                                       float* __restrict__ sums) {
    int row = blockIdx.x, tid = threadIdx.x;
    const float* x = s + (size_t)row * EE;
    float acc = 0.f;
    for (int e = tid; e < EE; e += 256) acc += x[e];
    __shared__ float red[256];
    red[tid] = acc; __syncthreads();
    for (int s2 = 128; s2 > 0; s2 >>= 1) {
        if (tid < s2) red[tid] += red[tid + s2];
        __syncthreads();
    }
    if (tid == 0) sums[row] = fmaxf(red[0], 1e-7f);
}

__global__ void normalize_kernel(float* __restrict__ s, const float* __restrict__ sums) {
    int row = blockIdx.y;
    int e = blockIdx.x * 256 + threadIdx.x;
    if (e < EE) s[(size_t)row * EE + e] /= sums[row];
}

// ---------------- exact k-th largest per row (radix select on float bits) ----------------
// All state values are nonneg, so the uint bit pattern is order-isomorphic.
__global__ __launch_bounds__(256) void topk_kernel(const float* __restrict__ s,
                                                   float* __restrict__ th) {
    int row = blockIdx.x, tid = threadIdx.x;
    const float* x = s + (size_t)row * EE;
    __shared__ unsigned hist[256];
    __shared__ unsigned sh_prefix;
    __shared__ int sh_remk;
    unsigned prefix = 0;
    int remk = KTOP;
    for (int round = 0; round < 4; ++round) {
        hist[tid] = 0;
        __syncthreads();
        int shift = 24 - 8 * round;
        for (int e = tid; e < EE; e += 256) {
            unsigned key = __float_as_uint(x[e]);
            unsigned hi = key >> shift;            // bits above 'shift'
            bool take = (round == 0) || ((hi >> 8) == prefix);
            if (take) atomicAdd(&hist[hi & 255u], 1u);
        }
        __syncthreads();
        if (tid == 0) {
            int acc = 0; int bin = 255;
            for (; bin > 0; --bin) {
                int c = (int)hist[bin];
                if (acc + c >= remk) break;
                acc += c;
            }
            sh_prefix = (prefix << 8) | (unsigned)bin;
            sh_remk = remk - acc;
        }
        __syncthreads();
        prefix = sh_prefix; remk = sh_remk;
        __syncthreads();
    }
    if (tid == 0) th[row] = __uint_as_float(prefix);
}

// ---------------- prune + seed identity term + batch mask ----------------
__global__ void prune_kernel(float* __restrict__ s, const float* __restrict__ th,
                             const float* __restrict__ w_t, float* __restrict__ x,
                             int* __restrict__ mask) {
    int row = blockIdx.y;
    int e = blockIdx.x * 256 + threadIdx.x;
    if (e >= EE) return;
    float thr = th[row];
    float w400 = w_t[row * NRELC + (NRELC - 1)];
    size_t idx = (size_t)row * EE + e;
    float v = s[idx];
    float xv = (v >= thr) ? v : 0.f;
    x[idx] = xv;
    s[idx] = w400 * xv;                 // identity-relation seeding
    if (xv > 0.f) atomicOr(&mask[e], 1 << (row / 3));
}

// ---------------- hops 1..2: masked sparse scan ----------------
__global__ __launch_bounds__(256) void hop_scan(
    const int* __restrict__ heads, const int* __restrict__ tails,
    const int* __restrict__ tails2, const int* __restrict__ rels,
    const int* __restrict__ mask, const float* __restrict__ x,
    const float* __restrict__ w_t, float* __restrict__ s)
{
    int i = blockIdx.x * 256 + threadIdx.x;
    if (i >= NN) return;
    int h = heads[i], t2 = tails2[i];
    int mh = mask[h], mt = mask[t2];
    if ((mh | mt) == 0) return;
    int tl = tails[i], rr = rels[i];
    for (int b = 0; b < BB; ++b) {
        if ((mh >> b) & 1) {
            for (int l = 0; l < LL; ++l) {
                int row = b * 3 + l;
                float v = x[(size_t)row * EE + h];
                if (v != 0.f)
                    atomicAdd(&s[(size_t)row * EE + tl], v * w_t[row * NRELC + rr]);
            }
        }
        if ((mt >> b) & 1) {
            for (int l = 0; l < LL; ++l) {
                int row = b * 3 + l;
                float v = x[(size_t)row * EE + t2];
                if (v != 0.f)
                    atomicAdd(&s[(size_t)row * EE + h], v * w_t[row * NRELC + rr + RR]);
            }
        }
    }
}

// ---------------- final: sum over L ----------------
__global__ void final_kernel(const float* __restrict__ s, float* __restrict__ out) {
    int b = blockIdx.y;
    int e = blockIdx.x * 256 + threadIdx.x;
    if (e < EE)
        out[(size_t)b * EE + e] = s[(size_t)(b * 3 + 0) * EE + e]
                                + s[(size_t)(b * 3 + 1) * EE + e]
                                + s[(size_t)(b * 3 + 2) * EE + e];
}

extern "C" void kernel_launch(void* const* d_in, const int* in_sizes, int n_in,
                              void* d_out, int out_size, void* d_ws, size_t ws_size,
                              hipStream_t stream)
{
    const int*   input_x  = (const int*)d_in[0];
    const int*   input_r  = (const int*)d_in[1];
    const int*   e2triple = (const int*)d_in[2];
    const int*   triple2e = (const int*)d_in[3];
    const int*   r2triple = (const int*)d_in[4];
    const float* emb      = (const float*)d_in[5];
    const float* Wih_f    = (const float*)d_in[6];
    const float* Whh_f    = (const float*)d_in[7];
    const float* bih_f    = (const float*)d_in[8];
    const float* bhh_f    = (const float*)d_in[9];
    const float* Wih_b    = (const float*)d_in[10];
    const float* Whh_b    = (const float*)d_in[11];
    const float* bih_b    = (const float*)d_in[12];
    const float* bhh_b    = (const float*)d_in[13];
    const float* linW     = (const float*)d_in[14];
    const float* linb     = (const float*)d_in[15];

    const int* heads  = e2triple;                    // e2triple[0]
    const int* tails2 = e2triple + 2 * (size_t)NN;   // e2triple[2]
    const int* tails  = triple2e + (size_t)NN;       // triple2e[1]
    const int* rels   = r2triple;                    // r2triple[0]

    // workspace layout (floats): ~10.1 MB total
    float* ws   = (float*)d_ws;
    float* hbuf = ws;                         // 3*2*8*3*256   = 36864
    float* wbuf = hbuf + 36864;               // 3*24*401      = 28872
    float* xst  = wbuf + 28872;               // 24*50000      = 1200000
    float* sst  = xst + 1200000;              // 24*50000      = 1200000
    float* sums = sst + 1200000;              // 24
    float* th   = sums + 24;                  // 24
    int*   mask = (int*)(th + 24);            // 50000 ints

    float* out = (float*)d_out;
    const int EBLK = (EE + 255) / 256;        // 196
    const int SBLK = (24 * EE + 255) / 256;   // state fill blocks
    const int NBLK = (NN + 255) / 256;

    // Phase A
    lstm_kernel<<<48, 256, 0, stream>>>(input_r, emb, Wih_f, Whh_f, bih_f, bhh_f,
                                        Wih_b, Whh_b, bih_b, bhh_b, hbuf);
    logits_kernel<<<72, 256, 0, stream>>>(hbuf, linW, linb, wbuf);

    // hop 0 (one-hot input)
    fill_zero_f<<<SBLK, 256, 0, stream>>>(sst, 24 * EE);
    seed0_kernel<<<1, 32, 0, stream>>>(input_x, wbuf, sst);
    hop0_scan<<<NBLK, 256, 0, stream>>>(heads, tails, tails2, rels, input_x, wbuf, sst);
    row_sums_kernel<<<24, 256, 0, stream>>>(sst, sums);
    normalize_kernel<<<dim3(EBLK, 24), 256, 0, stream>>>(sst, sums);

    // hops 1,2
    for (int t = 1; t < TT; ++t) {
        const float* w_t = wbuf + (size_t)t * 24 * NRELC;
        fill_zero_i<<<EBLK, 256, 0, stream>>>(mask, EE);
        topk_kernel<<<24, 256, 0, stream>>>(sst, th);
        prune_kernel<<<dim3(EBLK, 24), 256, 0, stream>>>(sst, th, w_t, xst, mask);
        hop_scan<<<NBLK, 256, 0, stream>>>(heads, tails, tails2, rels, mask, xst, w_t, sst);
        row_sums_kernel<<<24, 256, 0, stream>>>(sst, sums);
        normalize_kernel<<<dim3(EBLK, 24), 256, 0, stream>>>(sst, sums);
    }

    final_kernel<<<dim3(EBLK, BB), 256, 0, stream>>>(sst, out);
}

// Round 4
// 832.788 us; speedup vs baseline: 1.4738x; 1.4738x over previous
//
#include <hip/hip_runtime.h>
#include <math.h>

#define TT 3
#define LL 3
#define EE 50000
#define NN 1000000
#define RR 200
#define NRELC 401
#define HH 256
#define BB 8
#define KTOP 1000

__device__ __forceinline__ float sigmoidf_(float x) {
    if (x >= 0.f) { return 1.f / (1.f + expf(-x)); }
    float z = expf(x); return z / (1.f + z);
}

// ================= Phase A: LSTM as wave-per-row GEMV pipeline =================
// 6 (l,dir) matrices x 1024 gate-rows = 6144 rows. Each wave handles 4 rows;
// lanes read the weight row coalesced (lane i -> float4 at i*16B).
// pre_kernel: preq[ld][b][row] = Wih[row].xq[b]+bih+bhh; pree[ld][row] for xe.
__global__ __launch_bounds__(256) void pre_kernel(
    const int* __restrict__ input_r, const float* __restrict__ emb,
    const float* __restrict__ Wih_f, const float* __restrict__ bih_f, const float* __restrict__ bhh_f,
    const float* __restrict__ Wih_b, const float* __restrict__ bih_b, const float* __restrict__ bhh_b,
    float* __restrict__ preq, float* __restrict__ pree)
{
    int wave = blockIdx.x * 4 + (threadIdx.x >> 6);
    if (wave >= 1536) return;                 // 6144 rows / 4
    int lane = threadIdx.x & 63;
    int row0 = wave * 4;
    int ld = row0 >> 10;                      // 0..5 = l*2+dir
    int l = ld >> 1, dir = ld & 1;
    const float* Wih = (dir ? Wih_b : Wih_f) + (size_t)l * 4 * HH * HH;
    const float* bih = (dir ? bih_b : bih_f) + l * 4 * HH;
    const float* bhh = (dir ? bhh_b : bhh_f) + l * 4 * HH;

    float4 xf[9];
    for (int b = 0; b < 8; ++b) {
        int r = input_r[b];
        xf[b] = *(const float4*)(emb + (size_t)r * HH + lane * 4);
    }
    xf[8] = *(const float4*)(emb + (size_t)(NRELC - 1) * HH + lane * 4);

    for (int rr = 0; rr < 4; ++rr) {
        int row = (row0 + rr) & 1023;
        float4 w4 = *(const float4*)(Wih + (size_t)row * HH + lane * 4);
        float acc[9];
        #pragma unroll
        for (int c = 0; c < 9; ++c)
            acc[c] = w4.x * xf[c].x + w4.y * xf[c].y + w4.z * xf[c].z + w4.w * xf[c].w;
        #pragma unroll
        for (int off = 32; off > 0; off >>= 1)
            #pragma unroll
            for (int c = 0; c < 9; ++c) acc[c] += __shfl_xor(acc[c], off);
        float bsum = bih[row] + bhh[row];
        if (lane < 8) preq[((size_t)ld * 8 + lane) * 1024 + row] = acc[lane] + bsum;
        if (lane == 8) pree[(size_t)ld * 1024 + row] = acc[8] + bsum;
    }
}

// rec_kernel: gates[ld][b][row] = Whh[row].h[ld][b] + pre  (steps 1..3)
__global__ __launch_bounds__(256) void rec_kernel(
    const float* __restrict__ Whh_f, const float* __restrict__ Whh_b,
    const float* __restrict__ preq, const float* __restrict__ pree,
    const float* __restrict__ hstate, float* __restrict__ gates, int step)
{
    int wave = blockIdx.x * 4 + (threadIdx.x >> 6);
    if (wave >= 1536) return;
    int lane = threadIdx.x & 63;
    int row0 = wave * 4;
    int ld = row0 >> 10;                      // 0..5
    int l = ld >> 1, dir = ld & 1;
    const float* Whh = (dir ? Whh_b : Whh_f) + (size_t)l * 4 * HH * HH;
    bool use_e = dir ? (step == 0) : (step == 3);

    float4 hf[8];
    for (int b = 0; b < 8; ++b)
        hf[b] = *(const float4*)(hstate + ((size_t)ld * 8 + b) * HH + lane * 4);

    for (int rr = 0; rr < 4; ++rr) {
        int row = (row0 + rr) & 1023;
        float4 w4 = *(const float4*)(Whh + (size_t)row * HH + lane * 4);
        float acc[8];
        #pragma unroll
        for (int b = 0; b < 8; ++b)
            acc[b] = w4.x * hf[b].x + w4.y * hf[b].y + w4.z * hf[b].z + w4.w * hf[b].w;
        #pragma unroll
        for (int off = 32; off > 0; off >>= 1)
            #pragma unroll
            for (int b = 0; b < 8; ++b) acc[b] += __shfl_xor(acc[b], off);
        if (lane < 8) {
            float pre = use_e ? pree[(size_t)ld * 1024 + row]
                              : preq[((size_t)ld * 8 + lane) * 1024 + row];
            gates[((size_t)ld * 8 + lane) * 1024 + row] = acc[lane] + pre;
        }
    }
}

// hupdate: LSTM nonlinearity, update h,c, store hbuf slot. 6*8*256 = 12288 threads.
__global__ __launch_bounds__(256) void hupdate_kernel(
    const float* __restrict__ preq, const float* __restrict__ pree,
    const float* __restrict__ gates, float* __restrict__ hstate,
    float* __restrict__ cstate, float* __restrict__ hbuf, int step)
{
    int g = blockIdx.x * 256 + threadIdx.x;   // (ld, b, j)
    int ld = g >> 11;                         // 0..5
    int b = (g >> 8) & 7;
    int j = g & 255;
    int dir = ld & 1;
    bool use_e = dir ? (step == 0) : (step == 3);
    float gv[4];
    #pragma unroll
    for (int q = 0; q < 4; ++q) {
        int row = q * 256 + j;
        if (step == 0)
            gv[q] = use_e ? pree[(size_t)ld * 1024 + row]
                          : preq[((size_t)ld * 8 + b) * 1024 + row];
        else
            gv[q] = gates[((size_t)ld * 8 + b) * 1024 + row];
    }
    float c = (step == 0) ? 0.f : cstate[g];
    float iv = sigmoidf_(gv[0]), fv = sigmoidf_(gv[1]);
    float gg = tanhf(gv[2]),     ov = sigmoidf_(gv[3]);
    c = fv * c + iv * gg;
    float h = ov * tanhf(c);
    cstate[g] = c;
    hstate[g] = h;
    int t_out = dir ? (3 - step) : step;
    if (t_out <= 2) hbuf[(((size_t)ld * 8 + b) * 3 + t_out) * HH + j] = h;
}

// logits: wave per (t, chunk-of-8-combos, n); lane covers concat[lane*8..+7].
__global__ __launch_bounds__(256) void logits_dot(
    const float* __restrict__ hbuf, const float* __restrict__ linW,
    const float* __restrict__ linb, float* __restrict__ wbuf)
{
    int wave = blockIdx.x * 4 + (threadIdx.x >> 6);
    if (wave >= 3 * 3 * NRELC) return;
    int lane = threadIdx.x & 63;
    int n = wave % NRELC;
    int tc = wave / NRELC;          // 0..8
    int t = tc / 3, chunk = tc % 3;
    const float4* wr = (const float4*)(linW + (size_t)n * 2 * HH + lane * 8);
    float4 w4a = wr[0], w4b = wr[1];
    float acc[8];
    #pragma unroll
    for (int i = 0; i < 8; ++i) {
        int combo = chunk * 8 + i;      // combo = b*3 + l
        int b = combo / 3, l = combo % 3;
        int ldh = (lane < 32) ? (l * 2 + 0) : (l * 2 + 1);
        const float* hsrc = hbuf + (((size_t)ldh * 8 + b) * 3 + t) * HH + (lane & 31) * 8;
        float4 f0 = *(const float4*)hsrc;
        float4 f1 = *(const float4*)(hsrc + 4);
        acc[i] = w4a.x * f0.x + w4a.y * f0.y + w4a.z * f0.z + w4a.w * f0.w
               + w4b.x * f1.x + w4b.y * f1.y + w4b.z * f1.z + w4b.w * f1.w;
    }
    #pragma unroll
    for (int off = 32; off > 0; off >>= 1)
        #pragma unroll
        for (int i = 0; i < 8; ++i) acc[i] += __shfl_xor(acc[i], off);
    if (lane < 8) {
        int combo = chunk * 8 + lane;
        wbuf[((size_t)t * 24 + combo) * NRELC + n] = acc[lane] + linb[n];
    }
}

__global__ __launch_bounds__(256) void softmax_kernel(float* __restrict__ wbuf) {
    int rowi = blockIdx.x;                        // t*24 + combo
    float* w = wbuf + (size_t)rowi * NRELC;
    __shared__ float red[256];
    int tid = threadIdx.x;
    float v0 = w[tid];
    float v1 = (tid + 256 < NRELC) ? w[tid + 256] : -1e30f;
    red[tid] = fmaxf(v0, v1); __syncthreads();
    for (int s2 = 128; s2 > 0; s2 >>= 1) {
        if (tid < s2) red[tid] = fmaxf(red[tid], red[tid + s2]);
        __syncthreads();
    }
    float m = red[0]; __syncthreads();
    float e0 = expf((v0 - m) * 0.1f);
    float e1 = (tid + 256 < NRELC) ? expf((v1 - m) * 0.1f) : 0.f;
    red[tid] = e0 + e1; __syncthreads();
    for (int s2 = 128; s2 > 0; s2 >>= 1) {
        if (tid < s2) red[tid] += red[tid + s2];
        __syncthreads();
    }
    float denom = red[0];
    w[tid] = e0 / denom;
    if (tid + 256 < NRELC) w[tid + 256] = e1 / denom;
}

// ================= utility fills =================
__global__ void fill_zero_f(float* __restrict__ p, int n) {
    int i = blockIdx.x * 256 + threadIdx.x;
    if (i < n) p[i] = 0.f;
}
__global__ void fill_zero_i(int* __restrict__ p, int n) {
    int i = blockIdx.x * 256 + threadIdx.x;
    if (i < n) p[i] = 0;
}

// ================= hop 0 (verbatim round 1) =================
__global__ void seed0_kernel(const int* __restrict__ input_x,
                             const float* __restrict__ w0, float* __restrict__ s) {
    int i = threadIdx.x;
    if (i < 24) {
        int b = i / 3;
        s[(size_t)i * EE + input_x[b]] = w0[(size_t)i * NRELC + (NRELC - 1)];
    }
}

__global__ __launch_bounds__(256) void hop0_scan(
    const int* __restrict__ heads, const int* __restrict__ tails,
    const int* __restrict__ tails2, const int* __restrict__ rels,
    const int* __restrict__ input_x, const float* __restrict__ w0,
    float* __restrict__ s)
{
    __shared__ int xs[BB];
    if (threadIdx.x < BB) xs[threadIdx.x] = input_x[threadIdx.x];
    __syncthreads();
    int i = blockIdx.x * 256 + threadIdx.x;
    if (i >= NN) return;
    int h = heads[i], t2 = tails2[i];
    bool any = false;
    #pragma unroll
    for (int b = 0; b < BB; ++b) any = any || (h == xs[b]) || (t2 == xs[b]);
    if (!any) return;
    int tl = tails[i], rr = rels[i];
    for (int b = 0; b < BB; ++b) {
        if (h == xs[b])
            for (int l = 0; l < LL; ++l)
                atomicAdd(&s[(size_t)(b * 3 + l) * EE + tl], w0[(b * 3 + l) * NRELC + rr]);
        if (t2 == xs[b])
            for (int l = 0; l < LL; ++l)
                atomicAdd(&s[(size_t)(b * 3 + l) * EE + h], w0[(b * 3 + l) * NRELC + rr + RR]);
    }
}

// ================= normalization (verbatim round 1) =================
__global__ __launch_bounds__(256) void row_sums_kernel(const float* __restrict__ s,
                                                       float* __restrict__ sums) {
    int row = blockIdx.x, tid = threadIdx.x;
    const float* x = s + (size_t)row * EE;
    float acc = 0.f;
    for (int e = tid; e < EE; e += 256) acc += x[e];
    __shared__ float red[256];
    red[tid] = acc; __syncthreads();
    for (int s2 = 128; s2 > 0; s2 >>= 1) {
        if (tid < s2) red[tid] += red[tid + s2];
        __syncthreads();
    }
    if (tid == 0) sums[row] = fmaxf(red[0], 1e-7f);
}

__global__ void normalize_kernel(float* __restrict__ s, const float* __restrict__ sums) {
    int row = blockIdx.y;
    int e = blockIdx.x * 256 + threadIdx.x;
    if (e < EE) s[(size_t)row * EE + e] /= sums[row];
}

// ================= exact k-th largest (verbatim round 1) =================
__global__ __launch_bounds__(256) void topk_kernel(const float* __restrict__ s,
                                                   float* __restrict__ th) {
    int row = blockIdx.x, tid = threadIdx.x;
    const float* x = s + (size_t)row * EE;
    __shared__ unsigned hist[256];
    __shared__ unsigned sh_prefix;
    __shared__ int sh_remk;
    unsigned prefix = 0;
    int remk = KTOP;
    for (int round = 0; round < 4; ++round) {
        hist[tid] = 0;
        __syncthreads();
        int shift = 24 - 8 * round;
        for (int e = tid; e < EE; e += 256) {
            unsigned key = __float_as_uint(x[e]);
            unsigned hi = key >> shift;
            bool take = (round == 0) || ((hi >> 8) == prefix);
            if (take) atomicAdd(&hist[hi & 255u], 1u);
        }
        __syncthreads();
        if (tid == 0) {
            int acc = 0; int bin = 255;
            for (; bin > 0; --bin) {
                int c = (int)hist[bin];
                if (acc + c >= remk) break;
                acc += c;
            }
            sh_prefix = (prefix << 8) | (unsigned)bin;
            sh_remk = remk - acc;
        }
        __syncthreads();
        prefix = sh_prefix; remk = sh_remk;
        __syncthreads();
    }
    if (tid == 0) th[row] = __uint_as_float(prefix);
}

// ================= prune + identity seed + mask (verbatim round 1) =================
__global__ void prune_kernel(float* __restrict__ s, const float* __restrict__ th,
                             const float* __restrict__ w_t, float* __restrict__ x,
                             int* __restrict__ mask) {
    int row = blockIdx.y;
    int e = blockIdx.x * 256 + threadIdx.x;
    if (e >= EE) return;
    float thr = th[row];
    float w400 = w_t[row * NRELC + (NRELC - 1)];
    size_t idx = (size_t)row * EE + e;
    float v = s[idx];
    float xv = (v >= thr) ? v : 0.f;
    x[idx] = xv;
    s[idx] = w400 * xv;
    if (xv > 0.f) atomicOr(&mask[e], 1 << (row / 3));
}

// ================= hops 1..2: masked sparse scan (verbatim round 1) =================
__global__ __launch_bounds__(256) void hop_scan(
    const int* __restrict__ heads, const int* __restrict__ tails,
    const int* __restrict__ tails2, const int* __restrict__ rels,
    const int* __restrict__ mask, const float* __restrict__ x,
    const float* __restrict__ w_t, float* __restrict__ s)
{
    int i = blockIdx.x * 256 + threadIdx.x;
    if (i >= NN) return;
    int h = heads[i], t2 = tails2[i];
    int mh = mask[h], mt = mask[t2];
    if ((mh | mt) == 0) return;
    int tl = tails[i], rr = rels[i];
    for (int b = 0; b < BB; ++b) {
        if ((mh >> b) & 1) {
            for (int l = 0; l < LL; ++l) {
                int row = b * 3 + l;
                float v = x[(size_t)row * EE + h];
                if (v != 0.f)
                    atomicAdd(&s[(size_t)row * EE + tl], v * w_t[row * NRELC + rr]);
            }
        }
        if ((mt >> b) & 1) {
            for (int l = 0; l < LL; ++l) {
                int row = b * 3 + l;
                float v = x[(size_t)row * EE + t2];
                if (v != 0.f)
                    atomicAdd(&s[(size_t)row * EE + h], v * w_t[row * NRELC + rr + RR]);
            }
        }
    }
}

// ================= final (verbatim round 1) =================
__global__ void final_kernel(const float* __restrict__ s, float* __restrict__ out) {
    int b = blockIdx.y;
    int e = blockIdx.x * 256 + threadIdx.x;
    if (e < EE)
        out[(size_t)b * EE + e] = s[(size_t)(b * 3 + 0) * EE + e]
                                + s[(size_t)(b * 3 + 1) * EE + e]
                                + s[(size_t)(b * 3 + 2) * EE + e];
}

extern "C" void kernel_launch(void* const* d_in, const int* in_sizes, int n_in,
                              void* d_out, int out_size, void* d_ws, size_t ws_size,
                              hipStream_t stream)
{
    const int*   input_x  = (const int*)d_in[0];
    const int*   input_r  = (const int*)d_in[1];
    const int*   e2triple = (const int*)d_in[2];
    const int*   triple2e = (const int*)d_in[3];
    const int*   r2triple = (const int*)d_in[4];
    const float* emb      = (const float*)d_in[5];
    const float* Wih_f    = (const float*)d_in[6];
    const float* Whh_f    = (const float*)d_in[7];
    const float* bih_f    = (const float*)d_in[8];
    const float* bhh_f    = (const float*)d_in[9];
    const float* Wih_b    = (const float*)d_in[10];
    const float* Whh_b    = (const float*)d_in[11];
    const float* bih_b    = (const float*)d_in[12];
    const float* bhh_b    = (const float*)d_in[13];
    const float* linW     = (const float*)d_in[14];
    const float* linb     = (const float*)d_in[15];

    const int* heads  = e2triple;
    const int* tails2 = e2triple + 2 * (size_t)NN;
    const int* tails  = triple2e + (size_t)NN;
    const int* rels   = r2triple;

    // workspace layout — identical footprint to the PASSING round-1 layout
    float* ws   = (float*)d_ws;
    float* hbuf = ws;                         // 36864 (6*8*3*256)
    float* wbuf = hbuf + 36864;               // 28872 (72*401)
    float* xst  = wbuf + 28872;               // 1200000
    float* sst  = xst + 1200000;              // 1200000
    float* sums = sst + 1200000;              // 24
    float* th   = sums + 24;                  // 24
    int*   mask = (int*)(th + 24);            // 50000 ints
    // phase-A scratch aliased into xst (dead until prune at t=1 overwrites x fully)
    float* preq   = xst;                      // 6*8*1024 = 49152
    float* pree   = preq + 49152;             // 6*1024   = 6144
    float* gates  = pree + 6144;              // 49152
    float* hstate = gates + 49152;            // 6*8*256  = 12288
    float* cstate = hstate + 12288;           // 12288   (total 129024 < 1200000)

    float* out = (float*)d_out;
    const int EBLK = (EE + 255) / 256;        // 196
    const int SBLK = (24 * EE + 255) / 256;
    const int NBLK = (NN + 255) / 256;

    // Phase A (coalesced GEMV pipeline; 6 matrices x 1024 rows)
    pre_kernel<<<384, 256, 0, stream>>>(input_r, emb, Wih_f, bih_f, bhh_f,
                                        Wih_b, bih_b, bhh_b, preq, pree);
    hupdate_kernel<<<48, 256, 0, stream>>>(preq, pree, gates, hstate, cstate, hbuf, 0);
    for (int s = 1; s <= 3; ++s) {
        rec_kernel<<<384, 256, 0, stream>>>(Whh_f, Whh_b, preq, pree, hstate, gates, s);
        hupdate_kernel<<<48, 256, 0, stream>>>(preq, pree, gates, hstate, cstate, hbuf, s);
    }
    logits_dot<<<903, 256, 0, stream>>>(hbuf, linW, linb, wbuf);
    softmax_kernel<<<72, 256, 0, stream>>>(wbuf);

    // hop 0 (one-hot input)
    fill_zero_f<<<SBLK, 256, 0, stream>>>(sst, 24 * EE);
    seed0_kernel<<<1, 32, 0, stream>>>(input_x, wbuf, sst);
    hop0_scan<<<NBLK, 256, 0, stream>>>(heads, tails, tails2, rels, input_x, wbuf, sst);
    row_sums_kernel<<<24, 256, 0, stream>>>(sst, sums);
    normalize_kernel<<<dim3(EBLK, 24), 256, 0, stream>>>(sst, sums);

    // hops 1,2
    for (int t = 1; t < TT; ++t) {
        const float* w_t = wbuf + (size_t)t * 24 * NRELC;
        fill_zero_i<<<EBLK, 256, 0, stream>>>(mask, EE);
        topk_kernel<<<24, 256, 0, stream>>>(sst, th);
        prune_kernel<<<dim3(EBLK, 24), 256, 0, stream>>>(sst, th, w_t, xst, mask);
        hop_scan<<<NBLK, 256, 0, stream>>>(heads, tails, tails2, rels, mask, xst, w_t, sst);
        row_sums_kernel<<<24, 256, 0, stream>>>(sst, sums);
        normalize_kernel<<<dim3(EBLK, 24), 256, 0, stream>>>(sst, sums);
    }

    final_kernel<<<dim3(EBLK, BB), 256, 0, stream>>>(sst, out);
}

// Round 5
// 831.928 us; speedup vs baseline: 1.4753x; 1.0010x over previous
//
#include <hip/hip_runtime.h>
#include <math.h>

#define TT 3
#define LL 3
#define EE 50000
#define NN 1000000
#define RR 200
#define NRELC 401
#define HH 256
#define BB 8
#define KTOP 1000

__device__ __forceinline__ float sigmoidf_(float x) {
    if (x >= 0.f) { return 1.f / (1.f + expf(-x)); }
    float z = expf(x); return z / (1.f + z);
}

// ================= Phase A: LSTM as wave-per-row GEMV pipeline =================
// 6 (l,dir) matrices x 1024 gate-rows = 6144 rows. Each wave handles 4 rows;
// lanes read the weight row coalesced (lane i -> float4 at i*16B).
__global__ __launch_bounds__(256) void pre_kernel(
    const int* __restrict__ input_r, const float* __restrict__ emb,
    const float* __restrict__ Wih_f, const float* __restrict__ bih_f, const float* __restrict__ bhh_f,
    const float* __restrict__ Wih_b, const float* __restrict__ bih_b, const float* __restrict__ bhh_b,
    float* __restrict__ preq, float* __restrict__ pree)
{
    int wave = blockIdx.x * 4 + (threadIdx.x >> 6);
    if (wave >= 1536) return;                 // 6144 rows / 4
    int lane = threadIdx.x & 63;
    int row0 = wave * 4;
    int ld = row0 >> 10;                      // 0..5 = l*2+dir
    int l = ld >> 1, dir = ld & 1;
    const float* Wih = (dir ? Wih_b : Wih_f) + (size_t)l * 4 * HH * HH;
    const float* bih = (dir ? bih_b : bih_f) + l * 4 * HH;
    const float* bhh = (dir ? bhh_b : bhh_f) + l * 4 * HH;

    float4 xf[9];
    for (int b = 0; b < 8; ++b) {
        int r = input_r[b];
        xf[b] = *(const float4*)(emb + (size_t)r * HH + lane * 4);
    }
    xf[8] = *(const float4*)(emb + (size_t)(NRELC - 1) * HH + lane * 4);

    for (int rr = 0; rr < 4; ++rr) {
        int row = (row0 + rr) & 1023;
        float4 w4 = *(const float4*)(Wih + (size_t)row * HH + lane * 4);
        float acc[9];
        #pragma unroll
        for (int c = 0; c < 9; ++c)
            acc[c] = w4.x * xf[c].x + w4.y * xf[c].y + w4.z * xf[c].z + w4.w * xf[c].w;
        #pragma unroll
        for (int off = 32; off > 0; off >>= 1)
            #pragma unroll
            for (int c = 0; c < 9; ++c) acc[c] += __shfl_xor(acc[c], off);
        float bsum = bih[row] + bhh[row];
        if (lane < 8) preq[((size_t)ld * 8 + lane) * 1024 + row] = acc[lane] + bsum;
        if (lane == 8) pree[(size_t)ld * 1024 + row] = acc[8] + bsum;
    }
}

__global__ __launch_bounds__(256) void rec_kernel(
    const float* __restrict__ Whh_f, const float* __restrict__ Whh_b,
    const float* __restrict__ preq, const float* __restrict__ pree,
    const float* __restrict__ hstate, float* __restrict__ gates, int step)
{
    int wave = blockIdx.x * 4 + (threadIdx.x >> 6);
    if (wave >= 1536) return;
    int lane = threadIdx.x & 63;
    int row0 = wave * 4;
    int ld = row0 >> 10;                      // 0..5
    int l = ld >> 1, dir = ld & 1;
    const float* Whh = (dir ? Whh_b : Whh_f) + (size_t)l * 4 * HH * HH;
    bool use_e = dir ? (step == 0) : (step == 3);

    float4 hf[8];
    for (int b = 0; b < 8; ++b)
        hf[b] = *(const float4*)(hstate + ((size_t)ld * 8 + b) * HH + lane * 4);

    for (int rr = 0; rr < 4; ++rr) {
        int row = (row0 + rr) & 1023;
        float4 w4 = *(const float4*)(Whh + (size_t)row * HH + lane * 4);
        float acc[8];
        #pragma unroll
        for (int b = 0; b < 8; ++b)
            acc[b] = w4.x * hf[b].x + w4.y * hf[b].y + w4.z * hf[b].z + w4.w * hf[b].w;
        #pragma unroll
        for (int off = 32; off > 0; off >>= 1)
            #pragma unroll
            for (int b = 0; b < 8; ++b) acc[b] += __shfl_xor(acc[b], off);
        if (lane < 8) {
            float pre = use_e ? pree[(size_t)ld * 1024 + row]
                              : preq[((size_t)ld * 8 + lane) * 1024 + row];
            gates[((size_t)ld * 8 + lane) * 1024 + row] = acc[lane] + pre;
        }
    }
}

__global__ __launch_bounds__(256) void hupdate_kernel(
    const float* __restrict__ preq, const float* __restrict__ pree,
    const float* __restrict__ gates, float* __restrict__ hstate,
    float* __restrict__ cstate, float* __restrict__ hbuf, int step)
{
    int g = blockIdx.x * 256 + threadIdx.x;   // (ld, b, j)
    int ld = g >> 11;                         // 0..5
    int b = (g >> 8) & 7;
    int j = g & 255;
    int dir = ld & 1;
    bool use_e = dir ? (step == 0) : (step == 3);
    float gv[4];
    #pragma unroll
    for (int q = 0; q < 4; ++q) {
        int row = q * 256 + j;
        if (step == 0)
            gv[q] = use_e ? pree[(size_t)ld * 1024 + row]
                          : preq[((size_t)ld * 8 + b) * 1024 + row];
        else
            gv[q] = gates[((size_t)ld * 8 + b) * 1024 + row];
    }
    float c = (step == 0) ? 0.f : cstate[g];
    float iv = sigmoidf_(gv[0]), fv = sigmoidf_(gv[1]);
    float gg = tanhf(gv[2]),     ov = sigmoidf_(gv[3]);
    c = fv * c + iv * gg;
    float h = ov * tanhf(c);
    cstate[g] = c;
    hstate[g] = h;
    int t_out = dir ? (3 - step) : step;
    if (t_out <= 2) hbuf[(((size_t)ld * 8 + b) * 3 + t_out) * HH + j] = h;
}

__global__ __launch_bounds__(256) void logits_dot(
    const float* __restrict__ hbuf, const float* __restrict__ linW,
    const float* __restrict__ linb, float* __restrict__ wbuf)
{
    int wave = blockIdx.x * 4 + (threadIdx.x >> 6);
    if (wave >= 3 * 3 * NRELC) return;
    int lane = threadIdx.x & 63;
    int n = wave % NRELC;
    int tc = wave / NRELC;          // 0..8
    int t = tc / 3, chunk = tc % 3;
    const float4* wr = (const float4*)(linW + (size_t)n * 2 * HH + lane * 8);
    float4 w4a = wr[0], w4b = wr[1];
    float acc[8];
    #pragma unroll
    for (int i = 0; i < 8; ++i) {
        int combo = chunk * 8 + i;      // combo = b*3 + l
        int b = combo / 3, l = combo % 3;
        int ldh = (lane < 32) ? (l * 2 + 0) : (l * 2 + 1);
        const float* hsrc = hbuf + (((size_t)ldh * 8 + b) * 3 + t) * HH + (lane & 31) * 8;
        float4 f0 = *(const float4*)hsrc;
        float4 f1 = *(const float4*)(hsrc + 4);
        acc[i] = w4a.x * f0.x + w4a.y * f0.y + w4a.z * f0.z + w4a.w * f0.w
               + w4b.x * f1.x + w4b.y * f1.y + w4b.z * f1.z + w4b.w * f1.w;
    }
    #pragma unroll
    for (int off = 32; off > 0; off >>= 1)
        #pragma unroll
        for (int i = 0; i < 8; ++i) acc[i] += __shfl_xor(acc[i], off);
    if (lane < 8) {
        int combo = chunk * 8 + lane;
        wbuf[((size_t)t * 24 + combo) * NRELC + n] = acc[lane] + linb[n];
    }
}

__global__ __launch_bounds__(256) void softmax_kernel(float* __restrict__ wbuf) {
    int rowi = blockIdx.x;                        // t*24 + combo
    float* w = wbuf + (size_t)rowi * NRELC;
    __shared__ float red[256];
    int tid = threadIdx.x;
    float v0 = w[tid];
    float v1 = (tid + 256 < NRELC) ? w[tid + 256] : -1e30f;
    red[tid] = fmaxf(v0, v1); __syncthreads();
    for (int s2 = 128; s2 > 0; s2 >>= 1) {
        if (tid < s2) red[tid] = fmaxf(red[tid], red[tid + s2]);
        __syncthreads();
    }
    float m = red[0]; __syncthreads();
    float e0 = expf((v0 - m) * 0.1f);
    float e1 = (tid + 256 < NRELC) ? expf((v1 - m) * 0.1f) : 0.f;
    red[tid] = e0 + e1; __syncthreads();
    for (int s2 = 128; s2 > 0; s2 >>= 1) {
        if (tid < s2) red[tid] += red[tid + s2];
        __syncthreads();
    }
    float denom = red[0];
    w[tid] = e0 / denom;
    if (tid + 256 < NRELC) w[tid + 256] = e1 / denom;
}

// ================= utility fills =================
__global__ void fill_zero_f(float* __restrict__ p, int n) {
    int i = blockIdx.x * 256 + threadIdx.x;
    if (i < n) p[i] = 0.f;
}
__global__ void fill_zero_i(int* __restrict__ p, int n) {
    int i = blockIdx.x * 256 + threadIdx.x;
    if (i < n) p[i] = 0;
}

// ================= hop 0 =================
__global__ void seed0_kernel(const int* __restrict__ input_x,
                             const float* __restrict__ w0, float* __restrict__ s) {
    int i = threadIdx.x;
    if (i < 24) {
        int b = i / 3;
        s[(size_t)i * EE + input_x[b]] = w0[(size_t)i * NRELC + (NRELC - 1)];
    }
}

__global__ __launch_bounds__(256) void hop0_scan(
    const int* __restrict__ heads, const int* __restrict__ tails,
    const int* __restrict__ tails2, const int* __restrict__ rels,
    const int* __restrict__ input_x, const float* __restrict__ w0,
    float* __restrict__ s)
{
    __shared__ int xs[BB];
    if (threadIdx.x < BB) xs[threadIdx.x] = input_x[threadIdx.x];
    __syncthreads();
    int i = blockIdx.x * 256 + threadIdx.x;
    if (i >= NN) return;
    int h = heads[i], t2 = tails2[i];
    bool any = false;
    #pragma unroll
    for (int b = 0; b < BB; ++b) any = any || (h == xs[b]) || (t2 == xs[b]);
    if (!any) return;
    int tl = tails[i], rr = rels[i];
    for (int b = 0; b < BB; ++b) {
        if (h == xs[b])
            for (int l = 0; l < LL; ++l)
                atomicAdd(&s[(size_t)(b * 3 + l) * EE + tl], w0[(b * 3 + l) * NRELC + rr]);
        if (t2 == xs[b])
            for (int l = 0; l < LL; ++l)
                atomicAdd(&s[(size_t)(b * 3 + l) * EE + h], w0[(b * 3 + l) * NRELC + rr + RR]);
    }
}

// ================= normalization =================
__global__ __launch_bounds__(256) void row_sums_kernel(const float* __restrict__ s,
                                                       float* __restrict__ sums) {
    int row = blockIdx.x, tid = threadIdx.x;
    const float* x = s + (size_t)row * EE;
    float acc = 0.f;
    for (int e = tid; e < EE; e += 256) acc += x[e];
    __shared__ float red[256];
    red[tid] = acc; __syncthreads();
    for (int s2 = 128; s2 > 0; s2 >>= 1) {
        if (tid < s2) red[tid] += red[tid + s2];
        __syncthreads();
    }
    if (tid == 0) sums[row] = fmaxf(red[0], 1e-7f);
}

__global__ void normalize_kernel(float* __restrict__ s, const float* __restrict__ sums) {
    int row = blockIdx.y;
    int e = blockIdx.x * 256 + threadIdx.x;
    if (e < EE) s[(size_t)row * EE + e] /= sums[row];
}

// ================= exact k-th largest: radix select with zero-skip =================
// ~98% of elements are exactly 0.0f. Counting them through the LDS histogram
// caused 64-way same-address atomic serialization (4.6M conflict cycles, 227us).
// Zeros can only land in bin 0 when prefix==0, so count them in a register and
// fold into hist[0] once per round. Bit-exact same histogram as before.
__global__ __launch_bounds__(256) void topk_kernel(const float* __restrict__ s,
                                                   float* __restrict__ th) {
    int row = blockIdx.x, tid = threadIdx.x;
    const float* x = s + (size_t)row * EE;
    __shared__ unsigned hist[256];
    __shared__ unsigned zred[256];
    __shared__ unsigned sh_prefix;
    __shared__ int sh_remk;
    unsigned prefix = 0;
    int remk = KTOP;
    for (int round = 0; round < 4; ++round) {
        hist[tid] = 0;
        __syncthreads();
        int shift = 24 - 8 * round;
        unsigned zc = 0;
        for (int e = tid; e < EE; e += 256) {
            unsigned key = __float_as_uint(x[e]);
            if (key == 0u) { zc += (prefix == 0u) ? 1u : 0u; continue; }
            unsigned hi = key >> shift;
            bool take = (round == 0) || ((hi >> 8) == prefix);
            if (take) atomicAdd(&hist[hi & 255u], 1u);
        }
        zred[tid] = zc; __syncthreads();
        for (int s2 = 128; s2 > 0; s2 >>= 1) {
            if (tid < s2) zred[tid] += zred[tid + s2];
            __syncthreads();
        }
        if (tid == 0) {
            hist[0] += zred[0];               // zeros (and only-if-prefix==0)
            int acc = 0; int bin = 255;
            for (; bin > 0; --bin) {
                int c = (int)hist[bin];
                if (acc + c >= remk) break;
                acc += c;
            }
            sh_prefix = (prefix << 8) | (unsigned)bin;
            sh_remk = remk - acc;
        }
        __syncthreads();
        prefix = sh_prefix; remk = sh_remk;
        __syncthreads();
    }
    if (tid == 0) th[row] = __uint_as_float(prefix);
}

// ================= prune + identity seed + mask =================
__global__ void prune_kernel(float* __restrict__ s, const float* __restrict__ th,
                             const float* __restrict__ w_t, float* __restrict__ x,
                             int* __restrict__ mask) {
    int row = blockIdx.y;
    int e = blockIdx.x * 256 + threadIdx.x;
    if (e >= EE) return;
    float thr = th[row];
    float w400 = w_t[row * NRELC + (NRELC - 1)];
    size_t idx = (size_t)row * EE + e;
    float v = s[idx];
    float xv = (v >= thr) ? v : 0.f;
    x[idx] = xv;
    s[idx] = w400 * xv;
    if (xv > 0.f) atomicOr(&mask[e], 1 << (row / 3));
}

// ================= hops 1..2: masked sparse scan =================
__global__ __launch_bounds__(256) void hop_scan(
    const int* __restrict__ heads, const int* __restrict__ tails,
    const int* __restrict__ tails2, const int* __restrict__ rels,
    const int* __restrict__ mask, const float* __restrict__ x,
    const float* __restrict__ w_t, float* __restrict__ s)
{
    int i = blockIdx.x * 256 + threadIdx.x;
    if (i >= NN) return;
    int h = heads[i], t2 = tails2[i];
    int mh = mask[h], mt = mask[t2];
    if ((mh | mt) == 0) return;
    int tl = tails[i], rr = rels[i];
    for (int b = 0; b < BB; ++b) {
        if ((mh >> b) & 1) {
            for (int l = 0; l < LL; ++l) {
                int row = b * 3 + l;
                float v = x[(size_t)row * EE + h];
                if (v != 0.f)
                    atomicAdd(&s[(size_t)row * EE + tl], v * w_t[row * NRELC + rr]);
            }
        }
        if ((mt >> b) & 1) {
            for (int l = 0; l < LL; ++l) {
                int row = b * 3 + l;
                float v = x[(size_t)row * EE + t2];
                if (v != 0.f)
                    atomicAdd(&s[(size_t)row * EE + h], v * w_t[row * NRELC + rr + RR]);
            }
        }
    }
}

// ================= final =================
__global__ void final_kernel(const float* __restrict__ s, float* __restrict__ out) {
    int b = blockIdx.y;
    int e = blockIdx.x * 256 + threadIdx.x;
    if (e < EE)
        out[(size_t)b * EE + e] = s[(size_t)(b * 3 + 0) * EE + e]
                                + s[(size_t)(b * 3 + 1) * EE + e]
                                + s[(size_t)(b * 3 + 2) * EE + e];
}

extern "C" void kernel_launch(void* const* d_in, const int* in_sizes, int n_in,
                              void* d_out, int out_size, void* d_ws, size_t ws_size,
                              hipStream_t stream)
{
    const int*   input_x  = (const int*)d_in[0];
    const int*   input_r  = (const int*)d_in[1];
    const int*   e2triple = (const int*)d_in[2];
    const int*   triple2e = (const int*)d_in[3];
    const int*   r2triple = (const int*)d_in[4];
    const float* emb      = (const float*)d_in[5];
    const float* Wih_f    = (const float*)d_in[6];
    const float* Whh_f    = (const float*)d_in[7];
    const float* bih_f    = (const float*)d_in[8];
    const float* bhh_f    = (const float*)d_in[9];
    const float* Wih_b    = (const float*)d_in[10];
    const float* Whh_b    = (const float*)d_in[11];
    const float* bih_b    = (const float*)d_in[12];
    const float* bhh_b    = (const float*)d_in[13];
    const float* linW     = (const float*)d_in[14];
    const float* linb     = (const float*)d_in[15];

    const int* heads  = e2triple;
    const int* tails2 = e2triple + 2 * (size_t)NN;
    const int* tails  = triple2e + (size_t)NN;
    const int* rels   = r2triple;

    // workspace layout — identical footprint to the PASSING round-1 layout
    float* ws   = (float*)d_ws;
    float* hbuf = ws;                         // 36864 (6*8*3*256)
    float* wbuf = hbuf + 36864;               // 28872 (72*401)
    float* xst  = wbuf + 28872;               // 1200000
    float* sst  = xst + 1200000;              // 1200000
    float* sums = sst + 1200000;              // 24
    float* th   = sums + 24;                  // 24
    int*   mask = (int*)(th + 24);            // 50000 ints
    // phase-A scratch aliased into xst (dead until prune at t=1 overwrites x fully)
    float* preq   = xst;                      // 6*8*1024 = 49152
    float* pree   = preq + 49152;             // 6*1024   = 6144
    float* gates  = pree + 6144;              // 49152
    float* hstate = gates + 49152;            // 6*8*256  = 12288
    float* cstate = hstate + 12288;           // 12288   (total 129024 < 1200000)

    float* out = (float*)d_out;
    const int EBLK = (EE + 255) / 256;        // 196
    const int SBLK = (24 * EE + 255) / 256;
    const int NBLK = (NN + 255) / 256;

    // Phase A (coalesced GEMV pipeline; 6 matrices x 1024 rows)
    pre_kernel<<<384, 256, 0, stream>>>(input_r, emb, Wih_f, bih_f, bhh_f,
                                        Wih_b, bih_b, bhh_b, preq, pree);
    hupdate_kernel<<<48, 256, 0, stream>>>(preq, pree, gates, hstate, cstate, hbuf, 0);
    for (int s = 1; s <= 3; ++s) {
        rec_kernel<<<384, 256, 0, stream>>>(Whh_f, Whh_b, preq, pree, hstate, gates, s);
        hupdate_kernel<<<48, 256, 0, stream>>>(preq, pree, gates, hstate, cstate, hbuf, s);
    }
    logits_dot<<<903, 256, 0, stream>>>(hbuf, linW, linb, wbuf);
    softmax_kernel<<<72, 256, 0, stream>>>(wbuf);

    // hop 0 (one-hot input)
    fill_zero_f<<<SBLK, 256, 0, stream>>>(sst, 24 * EE);
    seed0_kernel<<<1, 32, 0, stream>>>(input_x, wbuf, sst);
    hop0_scan<<<NBLK, 256, 0, stream>>>(heads, tails, tails2, rels, input_x, wbuf, sst);
    row_sums_kernel<<<24, 256, 0, stream>>>(sst, sums);
    normalize_kernel<<<dim3(EBLK, 24), 256, 0, stream>>>(sst, sums);

    // hops 1,2
    for (int t = 1; t < TT; ++t) {
        const float* w_t = wbuf + (size_t)t * 24 * NRELC;
        fill_zero_i<<<EBLK, 256, 0, stream>>>(mask, EE);
        topk_kernel<<<24, 256, 0, stream>>>(sst, th);
        prune_kernel<<<dim3(EBLK, 24), 256, 0, stream>>>(sst, th, w_t, xst, mask);
        hop_scan<<<NBLK, 256, 0, stream>>>(heads, tails, tails2, rels, mask, xst, w_t, sst);
        row_sums_kernel<<<24, 256, 0, stream>>>(sst, sums);
        normalize_kernel<<<dim3(EBLK, 24), 256, 0, stream>>>(sst, sums);
    }

    final_kernel<<<dim3(EBLK, BB), 256, 0, stream>>>(sst, out);
}

// Round 6
// 508.406 us; speedup vs baseline: 2.4141x; 1.6363x over previous
//
#include <hip/hip_runtime.h>
#include <math.h>

#define TT 3
#define LL 3
#define EE 50000
#define NN 1000000
#define RR 200
#define NRELC 401
#define HH 256
#define BB 8
#define KTOP 1000

__device__ __forceinline__ float sigmoidf_(float x) {
    if (x >= 0.f) { return 1.f / (1.f + expf(-x)); }
    float z = expf(x); return z / (1.f + z);
}

// ================= Phase A: LSTM as wave-per-row GEMV pipeline =================
// 6 (l,dir) matrices x 1024 gate-rows = 6144 rows. Each wave handles 4 rows;
// lanes read the weight row coalesced (lane i -> float4 at i*16B).
__global__ __launch_bounds__(256) void pre_kernel(
    const int* __restrict__ input_r, const float* __restrict__ emb,
    const float* __restrict__ Wih_f, const float* __restrict__ bih_f, const float* __restrict__ bhh_f,
    const float* __restrict__ Wih_b, const float* __restrict__ bih_b, const float* __restrict__ bhh_b,
    float* __restrict__ preq, float* __restrict__ pree)
{
    int wave = blockIdx.x * 4 + (threadIdx.x >> 6);
    if (wave >= 1536) return;                 // 6144 rows / 4
    int lane = threadIdx.x & 63;
    int row0 = wave * 4;
    int ld = row0 >> 10;                      // 0..5 = l*2+dir
    int l = ld >> 1, dir = ld & 1;
    const float* Wih = (dir ? Wih_b : Wih_f) + (size_t)l * 4 * HH * HH;
    const float* bih = (dir ? bih_b : bih_f) + l * 4 * HH;
    const float* bhh = (dir ? bhh_b : bhh_f) + l * 4 * HH;

    float4 xf[9];
    for (int b = 0; b < 8; ++b) {
        int r = input_r[b];
        xf[b] = *(const float4*)(emb + (size_t)r * HH + lane * 4);
    }
    xf[8] = *(const float4*)(emb + (size_t)(NRELC - 1) * HH + lane * 4);

    for (int rr = 0; rr < 4; ++rr) {
        int row = (row0 + rr) & 1023;
        float4 w4 = *(const float4*)(Wih + (size_t)row * HH + lane * 4);
        float acc[9];
        #pragma unroll
        for (int c = 0; c < 9; ++c)
            acc[c] = w4.x * xf[c].x + w4.y * xf[c].y + w4.z * xf[c].z + w4.w * xf[c].w;
        #pragma unroll
        for (int off = 32; off > 0; off >>= 1)
            #pragma unroll
            for (int c = 0; c < 9; ++c) acc[c] += __shfl_xor(acc[c], off);
        float bsum = bih[row] + bhh[row];
        if (lane < 8) preq[((size_t)ld * 8 + lane) * 1024 + row] = acc[lane] + bsum;
        if (lane == 8) pree[(size_t)ld * 1024 + row] = acc[8] + bsum;
    }
}

__global__ __launch_bounds__(256) void rec_kernel(
    const float* __restrict__ Whh_f, const float* __restrict__ Whh_b,
    const float* __restrict__ preq, const float* __restrict__ pree,
    const float* __restrict__ hstate, float* __restrict__ gates, int step)
{
    int wave = blockIdx.x * 4 + (threadIdx.x >> 6);
    if (wave >= 1536) return;
    int lane = threadIdx.x & 63;
    int row0 = wave * 4;
    int ld = row0 >> 10;                      // 0..5
    int l = ld >> 1, dir = ld & 1;
    const float* Whh = (dir ? Whh_b : Whh_f) + (size_t)l * 4 * HH * HH;
    bool use_e = dir ? (step == 0) : (step == 3);

    float4 hf[8];
    for (int b = 0; b < 8; ++b)
        hf[b] = *(const float4*)(hstate + ((size_t)ld * 8 + b) * HH + lane * 4);

    for (int rr = 0; rr < 4; ++rr) {
        int row = (row0 + rr) & 1023;
        float4 w4 = *(const float4*)(Whh + (size_t)row * HH + lane * 4);
        float acc[8];
        #pragma unroll
        for (int b = 0; b < 8; ++b)
            acc[b] = w4.x * hf[b].x + w4.y * hf[b].y + w4.z * hf[b].z + w4.w * hf[b].w;
        #pragma unroll
        for (int off = 32; off > 0; off >>= 1)
            #pragma unroll
            for (int b = 0; b < 8; ++b) acc[b] += __shfl_xor(acc[b], off);
        if (lane < 8) {
            float pre = use_e ? pree[(size_t)ld * 1024 + row]
                              : preq[((size_t)ld * 8 + lane) * 1024 + row];
            gates[((size_t)ld * 8 + lane) * 1024 + row] = acc[lane] + pre;
        }
    }
}

__global__ __launch_bounds__(256) void hupdate_kernel(
    const float* __restrict__ preq, const float* __restrict__ pree,
    const float* __restrict__ gates, float* __restrict__ hstate,
    float* __restrict__ cstate, float* __restrict__ hbuf, int step)
{
    int g = blockIdx.x * 256 + threadIdx.x;   // (ld, b, j)
    int ld = g >> 11;                         // 0..5
    int b = (g >> 8) & 7;
    int j = g & 255;
    int dir = ld & 1;
    bool use_e = dir ? (step == 0) : (step == 3);
    float gv[4];
    #pragma unroll
    for (int q = 0; q < 4; ++q) {
        int row = q * 256 + j;
        if (step == 0)
            gv[q] = use_e ? pree[(size_t)ld * 1024 + row]
                          : preq[((size_t)ld * 8 + b) * 1024 + row];
        else
            gv[q] = gates[((size_t)ld * 8 + b) * 1024 + row];
    }
    float c = (step == 0) ? 0.f : cstate[g];
    float iv = sigmoidf_(gv[0]), fv = sigmoidf_(gv[1]);
    float gg = tanhf(gv[2]),     ov = sigmoidf_(gv[3]);
    c = fv * c + iv * gg;
    float h = ov * tanhf(c);
    cstate[g] = c;
    hstate[g] = h;
    int t_out = dir ? (3 - step) : step;
    if (t_out <= 2) hbuf[(((size_t)ld * 8 + b) * 3 + t_out) * HH + j] = h;
}

__global__ __launch_bounds__(256) void logits_dot(
    const float* __restrict__ hbuf, const float* __restrict__ linW,
    const float* __restrict__ linb, float* __restrict__ wbuf)
{
    int wave = blockIdx.x * 4 + (threadIdx.x >> 6);
    if (wave >= 3 * 3 * NRELC) return;
    int lane = threadIdx.x & 63;
    int n = wave % NRELC;
    int tc = wave / NRELC;          // 0..8
    int t = tc / 3, chunk = tc % 3;
    const float4* wr = (const float4*)(linW + (size_t)n * 2 * HH + lane * 8);
    float4 w4a = wr[0], w4b = wr[1];
    float acc[8];
    #pragma unroll
    for (int i = 0; i < 8; ++i) {
        int combo = chunk * 8 + i;      // combo = b*3 + l
        int b = combo / 3, l = combo % 3;
        int ldh = (lane < 32) ? (l * 2 + 0) : (l * 2 + 1);
        const float* hsrc = hbuf + (((size_t)ldh * 8 + b) * 3 + t) * HH + (lane & 31) * 8;
        float4 f0 = *(const float4*)hsrc;
        float4 f1 = *(const float4*)(hsrc + 4);
        acc[i] = w4a.x * f0.x + w4a.y * f0.y + w4a.z * f0.z + w4a.w * f0.w
               + w4b.x * f1.x + w4b.y * f1.y + w4b.z * f1.z + w4b.w * f1.w;
    }
    #pragma unroll
    for (int off = 32; off > 0; off >>= 1)
        #pragma unroll
        for (int i = 0; i < 8; ++i) acc[i] += __shfl_xor(acc[i], off);
    if (lane < 8) {
        int combo = chunk * 8 + lane;
        wbuf[((size_t)t * 24 + combo) * NRELC + n] = acc[lane] + linb[n];
    }
}

__global__ __launch_bounds__(256) void softmax_kernel(float* __restrict__ wbuf) {
    int rowi = blockIdx.x;                        // t*24 + combo
    float* w = wbuf + (size_t)rowi * NRELC;
    __shared__ float red[256];
    int tid = threadIdx.x;
    float v0 = w[tid];
    float v1 = (tid + 256 < NRELC) ? w[tid + 256] : -1e30f;
    red[tid] = fmaxf(v0, v1); __syncthreads();
    for (int s2 = 128; s2 > 0; s2 >>= 1) {
        if (tid < s2) red[tid] = fmaxf(red[tid], red[tid + s2]);
        __syncthreads();
    }
    float m = red[0]; __syncthreads();
    float e0 = expf((v0 - m) * 0.1f);
    float e1 = (tid + 256 < NRELC) ? expf((v1 - m) * 0.1f) : 0.f;
    red[tid] = e0 + e1; __syncthreads();
    for (int s2 = 128; s2 > 0; s2 >>= 1) {
        if (tid < s2) red[tid] += red[tid + s2];
        __syncthreads();
    }
    float denom = red[0];
    w[tid] = e0 / denom;
    if (tid + 256 < NRELC) w[tid + 256] = e1 / denom;
}

// ================= utility fills =================
__global__ void fill_zero_f(float* __restrict__ p, int n) {
    int i = blockIdx.x * 256 + threadIdx.x;
    if (i < n) p[i] = 0.f;
}
__global__ void fill_zero_i(int* __restrict__ p, int n) {
    int i = blockIdx.x * 256 + threadIdx.x;
    if (i < n) p[i] = 0;
}

// ================= hop 0 =================
__global__ void seed0_kernel(const int* __restrict__ input_x,
                             const float* __restrict__ w0, float* __restrict__ s) {
    int i = threadIdx.x;
    if (i < 24) {
        int b = i / 3;
        s[(size_t)i * EE + input_x[b]] = w0[(size_t)i * NRELC + (NRELC - 1)];
    }
}

__global__ __launch_bounds__(256) void hop0_scan(
    const int* __restrict__ heads, const int* __restrict__ tails,
    const int* __restrict__ tails2, const int* __restrict__ rels,
    const int* __restrict__ input_x, const float* __restrict__ w0,
    float* __restrict__ s)
{
    __shared__ int xs[BB];
    if (threadIdx.x < BB) xs[threadIdx.x] = input_x[threadIdx.x];
    __syncthreads();
    int i = blockIdx.x * 256 + threadIdx.x;
    if (i >= NN) return;
    int h = heads[i], t2 = tails2[i];
    bool any = false;
    #pragma unroll
    for (int b = 0; b < BB; ++b) any = any || (h == xs[b]) || (t2 == xs[b]);
    if (!any) return;
    int tl = tails[i], rr = rels[i];
    for (int b = 0; b < BB; ++b) {
        if (h == xs[b])
            for (int l = 0; l < LL; ++l)
                atomicAdd(&s[(size_t)(b * 3 + l) * EE + tl], w0[(b * 3 + l) * NRELC + rr]);
        if (t2 == xs[b])
            for (int l = 0; l < LL; ++l)
                atomicAdd(&s[(size_t)(b * 3 + l) * EE + h], w0[(b * 3 + l) * NRELC + rr + RR]);
    }
}

// ================= normalization =================
__global__ __launch_bounds__(256) void row_sums_kernel(const float* __restrict__ s,
                                                       float* __restrict__ sums) {
    int row = blockIdx.x, tid = threadIdx.x;
    const float* x = s + (size_t)row * EE;
    float acc = 0.f;
    for (int e = tid; e < EE; e += 256) acc += x[e];
    __shared__ float red[256];
    red[tid] = acc; __syncthreads();
    for (int s2 = 128; s2 > 0; s2 >>= 1) {
        if (tid < s2) red[tid] += red[tid + s2];
        __syncthreads();
    }
    if (tid == 0) sums[row] = fmaxf(red[0], 1e-7f);
}

__global__ void normalize_kernel(float* __restrict__ s, const float* __restrict__ sums) {
    int row = blockIdx.y;
    int e = blockIdx.x * 256 + threadIdx.x;
    if (e < EE) s[(size_t)row * EE + e] /= sums[row];
}

// ================= exact k-th largest: 3-round radix select, parallel =================
// Round 5's single-kernel select was latency-bound: 24 blocks x 784 serial loads.
// Now each round is a (24 rows x 8 chunks)-block histogram + 24-block pick.
// Zeros are skipped entirely: they can only matter below all nonzeros, in which
// case no bin reaches remk and the default bin 0 yields th = 0.0f (exact).
__global__ __launch_bounds__(256) void topk_hist(
    const float* __restrict__ s, const unsigned* __restrict__ selp,
    unsigned* __restrict__ hist, int round)
{
    int row = blockIdx.x, chunk = blockIdx.y;     // 24 x 8
    int bits = (round == 0) ? 12 : 10;
    int nb = 1 << bits;
    int shift = (round == 0) ? 20 : (round == 1) ? 10 : 0;
    int pshift = shift + bits;                    // prefix check shift (r1: 20, r2: 10)
    __shared__ unsigned lh[4096];
    for (int i = threadIdx.x; i < nb; i += 256) lh[i] = 0;
    __syncthreads();
    unsigned prefix = (round == 0) ? 0u : selp[row];
    const float* x = s + (size_t)row * EE + chunk * 6250;
    for (int e = threadIdx.x; e < 6250; e += 256) {
        unsigned key = __float_as_uint(x[e]);
        if (key == 0u) continue;
        if (round != 0 && (key >> pshift) != prefix) continue;
        atomicAdd(&lh[(key >> shift) & (unsigned)(nb - 1)], 1u);
    }
    __syncthreads();
    for (int i = threadIdx.x; i < nb; i += 256)
        if (lh[i]) atomicAdd(&hist[(size_t)row * nb + i], lh[i]);
}

__global__ __launch_bounds__(256) void topk_pick(
    const unsigned* __restrict__ hist, unsigned* __restrict__ selp,
    int* __restrict__ selk, float* __restrict__ th, int* __restrict__ mask,
    int round)
{
    int row = blockIdx.x;
    int bits = (round == 0) ? 12 : 10;
    int nb = 1 << bits;
    int bpt = nb >> 8;                            // 16 or 4
    const unsigned* hrow = hist + (size_t)row * nb;
    int tid = threadIdx.x;
    unsigned cnt[16];
    int tot = 0;
    for (int i = 0; i < bpt; ++i) { cnt[i] = hrow[tid * bpt + i]; tot += (int)cnt[i]; }
    __shared__ int red[256];
    red[tid] = tot; __syncthreads();
    for (int off = 1; off < 256; off <<= 1) {     // inclusive suffix scan
        int v = (tid + off < 256) ? red[tid + off] : 0;
        __syncthreads();
        red[tid] += v;
        __syncthreads();
    }
    int above = (tid == 255) ? 0 : red[tid + 1];  // count in bins of higher threads
    int remk = (round == 0) ? KTOP : selk[row];
    __shared__ int sh_bin, sh_rem;
    if (tid == 0) { sh_bin = 0; sh_rem = remk; }  // default: k-th lies among zeros
    __syncthreads();
    int acc = above, pickbin = -1, newrem = 0;
    for (int i = bpt - 1; i >= 0; --i) {          // descending value order
        int nacc = acc + (int)cnt[i];
        if (pickbin < 0 && acc < remk && nacc >= remk) { pickbin = tid * bpt + i; newrem = remk - acc; }
        acc = nacc;
    }
    if (pickbin >= 0) { sh_bin = pickbin; sh_rem = newrem; }   // at most one thread
    __syncthreads();
    if (tid == 0) {
        unsigned prefix = (round == 0) ? 0u : selp[row];
        unsigned np = (prefix << bits) | (unsigned)sh_bin;
        selp[row] = np; selk[row] = sh_rem;
        if (round == 2) th[row] = __uint_as_float(np);
    }
    if (round == 2) {                             // fold mask zeroing into last pick
        int per = (EE + 23) / 24;                 // 2084
        int e0 = row * per, e1 = min(e0 + per, EE);
        for (int e = e0 + tid; e < e1; e += 256) mask[e] = 0;
    }
}

// ================= prune + identity seed + mask =================
__global__ void prune_kernel(float* __restrict__ s, const float* __restrict__ th,
                             const float* __restrict__ w_t, float* __restrict__ x,
                             int* __restrict__ mask) {
    int row = blockIdx.y;
    int e = blockIdx.x * 256 + threadIdx.x;
    if (e >= EE) return;
    float thr = th[row];
    float w400 = w_t[row * NRELC + (NRELC - 1)];
    size_t idx = (size_t)row * EE + e;
    float v = s[idx];
    float xv = (v >= thr) ? v : 0.f;
    x[idx] = xv;
    s[idx] = w400 * xv;
    if (xv > 0.f) atomicOr(&mask[e], 1 << (row / 3));
}

// ================= hops 1..2: masked sparse scan =================
__global__ __launch_bounds__(256) void hop_scan(
    const int* __restrict__ heads, const int* __restrict__ tails,
    const int* __restrict__ tails2, const int* __restrict__ rels,
    const int* __restrict__ mask, const float* __restrict__ x,
    const float* __restrict__ w_t, float* __restrict__ s)
{
    int i = blockIdx.x * 256 + threadIdx.x;
    if (i >= NN) return;
    int h = heads[i], t2 = tails2[i];
    int mh = mask[h], mt = mask[t2];
    if ((mh | mt) == 0) return;
    int tl = tails[i], rr = rels[i];
    for (int b = 0; b < BB; ++b) {
        if ((mh >> b) & 1) {
            for (int l = 0; l < LL; ++l) {
                int row = b * 3 + l;
                float v = x[(size_t)row * EE + h];
                if (v != 0.f)
                    atomicAdd(&s[(size_t)row * EE + tl], v * w_t[row * NRELC + rr]);
            }
        }
        if ((mt >> b) & 1) {
            for (int l = 0; l < LL; ++l) {
                int row = b * 3 + l;
                float v = x[(size_t)row * EE + t2];
                if (v != 0.f)
                    atomicAdd(&s[(size_t)row * EE + h], v * w_t[row * NRELC + rr + RR]);
            }
        }
    }
}

// ================= final =================
__global__ void final_kernel(const float* __restrict__ s, float* __restrict__ out) {
    int b = blockIdx.y;
    int e = blockIdx.x * 256 + threadIdx.x;
    if (e < EE)
        out[(size_t)b * EE + e] = s[(size_t)(b * 3 + 0) * EE + e]
                                + s[(size_t)(b * 3 + 1) * EE + e]
                                + s[(size_t)(b * 3 + 2) * EE + e];
}

extern "C" void kernel_launch(void* const* d_in, const int* in_sizes, int n_in,
                              void* d_out, int out_size, void* d_ws, size_t ws_size,
                              hipStream_t stream)
{
    const int*   input_x  = (const int*)d_in[0];
    const int*   input_r  = (const int*)d_in[1];
    const int*   e2triple = (const int*)d_in[2];
    const int*   triple2e = (const int*)d_in[3];
    const int*   r2triple = (const int*)d_in[4];
    const float* emb      = (const float*)d_in[5];
    const float* Wih_f    = (const float*)d_in[6];
    const float* Whh_f    = (const float*)d_in[7];
    const float* bih_f    = (const float*)d_in[8];
    const float* bhh_f    = (const float*)d_in[9];
    const float* Wih_b    = (const float*)d_in[10];
    const float* Whh_b    = (const float*)d_in[11];
    const float* bih_b    = (const float*)d_in[12];
    const float* bhh_b    = (const float*)d_in[13];
    const float* linW     = (const float*)d_in[14];
    const float* linb     = (const float*)d_in[15];

    const int* heads  = e2triple;
    const int* tails2 = e2triple + 2 * (size_t)NN;
    const int* tails  = triple2e + (size_t)NN;
    const int* rels   = r2triple;

    // workspace layout — identical footprint to the PASSING round-1 layout
    float* ws   = (float*)d_ws;
    float* hbuf = ws;                         // 36864 (6*8*3*256)
    float* wbuf = hbuf + 36864;               // 28872 (72*401)
    float* xst  = wbuf + 28872;               // 1200000
    float* sst  = xst + 1200000;              // 1200000
    float* sums = sst + 1200000;              // 24
    float* th   = sums + 24;                  // 24
    int*   mask = (int*)(th + 24);            // 50000 ints
    // phase-A scratch aliased into xst (dead until prune at t=1 overwrites x fully)
    float* preq   = xst;                      // 6*8*1024 = 49152
    float* pree   = preq + 49152;             // 6*1024   = 6144
    float* gates  = pree + 6144;              // 49152
    float* hstate = gates + 49152;            // 6*8*256  = 12288
    float* cstate = hstate + 12288;           // 12288   (total 129024 < 1200000)
    // topk scratch ALSO aliased into xst (dead between hop_scan t and prune t+1;
    // hist consumed before prune overwrites xst each hop)
    unsigned* gh0  = (unsigned*)xst;          // 24*4096 = 98304
    unsigned* gh1  = gh0 + 24 * 4096;         // 24*1024 = 24576
    unsigned* gh2  = gh1 + 24 * 1024;         // 24*1024 = 24576
    unsigned* selp = gh2 + 24 * 1024;         // 24
    int*      selk = (int*)(selp + 24);       // 24      (total 147504 < 1200000)
    const int GHN  = 24 * 4096 + 2 * 24 * 1024;   // 147456 ints to zero per hop

    float* out = (float*)d_out;
    const int EBLK = (EE + 255) / 256;        // 196
    const int SBLK = (24 * EE + 255) / 256;
    const int NBLK = (NN + 255) / 256;

    // Phase A (coalesced GEMV pipeline; 6 matrices x 1024 rows)
    pre_kernel<<<384, 256, 0, stream>>>(input_r, emb, Wih_f, bih_f, bhh_f,
                                        Wih_b, bih_b, bhh_b, preq, pree);
    hupdate_kernel<<<48, 256, 0, stream>>>(preq, pree, gates, hstate, cstate, hbuf, 0);
    for (int s = 1; s <= 3; ++s) {
        rec_kernel<<<384, 256, 0, stream>>>(Whh_f, Whh_b, preq, pree, hstate, gates, s);
        hupdate_kernel<<<48, 256, 0, stream>>>(preq, pree, gates, hstate, cstate, hbuf, s);
    }
    logits_dot<<<903, 256, 0, stream>>>(hbuf, linW, linb, wbuf);
    softmax_kernel<<<72, 256, 0, stream>>>(wbuf);

    // hop 0 (one-hot input)
    fill_zero_f<<<SBLK, 256, 0, stream>>>(sst, 24 * EE);
    seed0_kernel<<<1, 32, 0, stream>>>(input_x, wbuf, sst);
    hop0_scan<<<NBLK, 256, 0, stream>>>(heads, tails, tails2, rels, input_x, wbuf, sst);
    row_sums_kernel<<<24, 256, 0, stream>>>(sst, sums);
    normalize_kernel<<<dim3(EBLK, 24), 256, 0, stream>>>(sst, sums);

    // hops 1,2
    for (int t = 1; t < TT; ++t) {
        const float* w_t = wbuf + (size_t)t * 24 * NRELC;
        fill_zero_i<<<(GHN + 255) / 256, 256, 0, stream>>>((int*)gh0, GHN);
        topk_hist<<<dim3(24, 8), 256, 0, stream>>>(sst, selp, gh0, 0);
        topk_pick<<<24, 256, 0, stream>>>(gh0, selp, selk, th, mask, 0);
        topk_hist<<<dim3(24, 8), 256, 0, stream>>>(sst, selp, gh1, 1);
        topk_pick<<<24, 256, 0, stream>>>(gh1, selp, selk, th, mask, 1);
        topk_hist<<<dim3(24, 8), 256, 0, stream>>>(sst, selp, gh2, 2);
        topk_pick<<<24, 256, 0, stream>>>(gh2, selp, selk, th, mask, 2);
        prune_kernel<<<dim3(EBLK, 24), 256, 0, stream>>>(sst, th, w_t, xst, mask);
        hop_scan<<<NBLK, 256, 0, stream>>>(heads, tails, tails2, rels, mask, xst, w_t, sst);
        row_sums_kernel<<<24, 256, 0, stream>>>(sst, sums);
        normalize_kernel<<<dim3(EBLK, 24), 256, 0, stream>>>(sst, sums);
    }

    final_kernel<<<dim3(EBLK, BB), 256, 0, stream>>>(sst, out);
}